// Round 7
// baseline (359.776 us; speedup 1.0000x reference)
//
#include <hip/hip_runtime.h>
#include <hip/hip_bf16.h>
#include <cstdio>
#include <cstdint>

// Attention (B=4, S=2048, D=1024, full-dim, fp32 I/O) via bf16 MFMA GEMMs.
// Round 7: single change vs R6 — by-fastest work decode inside each XCD's
// contiguous chunk, so the current B-panel (256-512 KB) stays L2-resident
// across a whole sweep instead of re-fetching the full B matrix per by-row
// (diagnosed L2-thrash -> L3-BW bound at ~7.9 TB/s effective).

typedef __attribute__((ext_vector_type(8))) short short8;
typedef __attribute__((ext_vector_type(4))) float f32x4;

#define AS1(p) ((const __attribute__((address_space(1))) void*)(p))
#define AS3(p) ((__attribute__((address_space(3))) void*)(p))

__device__ __forceinline__ unsigned short f2bf(float f) {
  union { float f; uint32_t u; } c; c.f = f;
  uint32_t u = c.u + 0x7fffu + ((c.u >> 16) & 1u);  // RNE (no NaN inputs here)
  return (unsigned short)(u >> 16);
}
__device__ __forceinline__ float bf2f(unsigned short h) {
  union { uint32_t u; float f; } c; c.u = ((uint32_t)h) << 16;
  return c.f;
}

// ---------------- fused fp32 -> bf16 convert: x + 4 weights ----------------
__global__ void cvt_all(const float* __restrict__ x, const float* __restrict__ wq,
                        const float* __restrict__ wk, const float* __restrict__ wv,
                        const float* __restrict__ wo, unsigned short* __restrict__ xb,
                        unsigned short* __restrict__ wb) {
  const int b = blockIdx.x;
  const float* src;
  unsigned short* dst;
  int idx;
  if (b < 8192) {
    src = x; dst = xb; idx = b * 256 + threadIdx.x;
  } else {
    int r = b - 8192, wi = r >> 10;
    src = (wi == 0) ? wq : (wi == 1) ? wk : (wi == 2) ? wv : wo;
    dst = wb + (size_t)wi * 1048576;
    idx = (r & 1023) * 256 + threadIdx.x;
  }
  float4 v = ((const float4*)src)[idx];
  ushort4 o;
  o.x = f2bf(v.x); o.y = f2bf(v.y); o.z = f2bf(v.z); o.w = f2bf(v.w);
  ((ushort4*)dst)[idx] = o;
}

// ---------------- rowsum of bf16 expS -> 1/sum (f32) -----------------------
__global__ void rowsum_inv(const unsigned short* __restrict__ P,
                           float* __restrict__ rsInv) {
  const int w = threadIdx.x >> 6, l = threadIdx.x & 63;
  const size_t row = (size_t)blockIdx.x * 4 + w;
  const unsigned short* p = P + row * 2048 + l * 32;
  float s = 0.f;
#pragma unroll
  for (int j = 0; j < 4; ++j) {
    short8 v = *(const short8*)(p + j * 8);
#pragma unroll
    for (int k = 0; k < 8; ++k) s += bf2f((unsigned short)v[k]);
  }
#pragma unroll
  for (int d = 32; d; d >>= 1) s += __shfl_xor(s, d);
  if (l == 0) rsInv[row] = 1.0f / s;
}

// ---------------- pipelined 128x128 GEMM, C = f(scale * A @ B^T) -----------
// R5 core (510 TF): 2 slots x 32KB LDS -> 2 blocks/CU, reg-dbuf K-loop,
// counted vmcnt, fragment-linear LDS (0 conflicts).
// MODE 0: C = scale*acc. MODE 1: C = bf16(exp(scale*acc)). MODE 2:
// C = scale*acc*rsInv[row].
__device__ __forceinline__ void store_out(float* p, float v) { *p = v; }
__device__ __forceinline__ void store_out(unsigned short* p, float v) { *p = f2bf(v); }

template <typename OutT, int MODE>
__global__ __launch_bounds__(256, 2) void gemmP(
    const unsigned short* __restrict__ A, const unsigned short* __restrict__ B,
    OutT* __restrict__ C, int lda, int ldb, int ldc, int nT,  // nT = K/64, even
    long long aStride, long long bStride, long long cStride, float scale,
    const float* __restrict__ rsInv, long long rsStride) {
  __shared__ unsigned short lds[32768];  // 64 KB -> 2 blocks/CU
  const int l = threadIdx.x & 63, w = threadIdx.x >> 6;
  const int wr = w >> 1, wc = w & 1;

  // bijective XCD-aware swizzle: XCD x executes a contiguous work chunk.
  // Within the chunk, decode BY-FASTEST: one B-panel stays L2-resident for
  // a whole by-sweep (16-64 blocks); A-panels stream with short-term reuse.
  const int gx = gridDim.x, gy = gridDim.y;
  int f = blockIdx.x + gx * (blockIdx.y + gy * blockIdx.z);
  int nwg = gx * gy * gridDim.z;
  int work = ((nwg & 7) == 0) ? ((f & 7) * (nwg >> 3) + (f >> 3)) : f;
  const int by = work % gy;          // by fastest (was bx)
  int rem = work / gy;
  const int bx = rem % gx, bz = rem / gx;
  const long long r0 = (long long)by * 128, c0 = (long long)bx * 128;
  A += (size_t)bz * aStride;
  B += (size_t)bz * bStride;
  C += (size_t)bz * cStride;

  // stage sources: wave w owns row-frags {2w, 2w+1} of both A and B
  const unsigned short* aS = A + (size_t)(r0 + 2 * w * 16 + (l & 15)) * lda + (l >> 4) * 8;
  const unsigned short* bS = B + (size_t)(c0 + 2 * w * 16 + (l & 15)) * ldb + (l >> 4) * 8;
  const size_t a16 = (size_t)16 * lda, b16 = (size_t)16 * ldb;
  char* const ldsc = (char*)lds;
  const int dstW = w * 4096;

#define GLD(s_, d_) __builtin_amdgcn_global_load_lds(AS1(s_), AS3(d_), 16, 0, 0)
#define STG(slot_, t_)                                                         \
  do {                                                                         \
    const unsigned short* sa_ = aS + (size_t)(t_) * 64;                        \
    const unsigned short* sb_ = bS + (size_t)(t_) * 64;                        \
    char* da_ = ldsc + ((slot_) << 15) + dstW;                                 \
    char* db_ = da_ + 16384;                                                   \
    GLD(sa_, da_); GLD(sa_ + 32, da_ + 1024);                                  \
    GLD(sa_ + a16, da_ + 2048); GLD(sa_ + a16 + 32, da_ + 3072);               \
    GLD(sb_, db_); GLD(sb_ + 32, db_ + 1024);                                  \
    GLD(sb_ + b16, db_ + 2048); GLD(sb_ + b16 + 32, db_ + 3072);               \
  } while (0)

#define RDAB(aD_, bD_, slot_)                                                  \
  do {                                                                         \
    _Pragma("unroll") for (int m = 0; m < 4; ++m)                              \
    _Pragma("unroll") for (int kk = 0; kk < 2; ++kk)                           \
        aD_[m * 2 + kk] = *(const short8*)(ldsc + ((slot_) << 15) +            \
                              (((wr * 4 + m) * 2 + kk) << 10) + l * 16);       \
    _Pragma("unroll") for (int n = 0; n < 4; ++n)                              \
    _Pragma("unroll") for (int kk = 0; kk < 2; ++kk)                           \
        bD_[n * 2 + kk] = *(const short8*)(ldsc + ((slot_) << 15) + 16384 +    \
                              (((wc * 4 + n) * 2 + kk) << 10) + l * 16);       \
  } while (0)

#define MH(aR_, bR_, n0_)                                                      \
  __builtin_amdgcn_s_setprio(1);                                               \
  _Pragma("unroll") for (int m = 0; m < 4; ++m)                                \
  _Pragma("unroll") for (int n = 0; n < 2; ++n)                                \
  _Pragma("unroll") for (int kk = 0; kk < 2; ++kk)                             \
      acc[m][(n0_) + n] = __builtin_amdgcn_mfma_f32_16x16x32_bf16(             \
          aR_[m * 2 + kk], bR_[((n0_) + n) * 2 + kk], acc[m][(n0_) + n], 0, 0, 0); \
  __builtin_amdgcn_s_setprio(0);
#define BAR() asm volatile("s_barrier" ::: "memory")
#define LGKM0() asm volatile("s_waitcnt lgkmcnt(0)" ::: "memory")
#define VMC(n_) asm volatile("s_waitcnt vmcnt(" #n_ ")" ::: "memory")
#define SB() __builtin_amdgcn_sched_barrier(0)

  short8 aE[8], bE[8], aO[8], bO[8];
  f32x4 acc[4][4] = {};

  // prologue: stage tiles 0,1; read tile 0
  STG(0, 0); STG(1, 1);
  VMC(8); BAR();
  RDAB(aE, bE, 0);
  LGKM0(); SB(); BAR();

  for (int t = 0; t < nT; t += 2) {
    // ---- even tile t (slot 0, regs E) ----
    if (t + 2 < nT) { STG(0, t + 2); }
    MH(aE, bE, 0);
    if (t + 2 < nT) { VMC(8); } else { VMC(0); }   // stage(t+1) resident
    BAR();
    RDAB(aO, bO, 1);                               // tile t+1 from slot 1
    MH(aE, bE, 2);                                 // overlaps the reads
    LGKM0(); SB(); BAR();
    // ---- odd tile t+1 (slot 1, regs O) ----
    if (t + 3 < nT) { STG(1, t + 3); }
    MH(aO, bO, 0);
    if (t + 3 < nT) { VMC(8); BAR(); RDAB(aE, bE, 0); }
    else if (t + 2 < nT) { VMC(0); BAR(); RDAB(aE, bE, 0); }
    MH(aO, bO, 2);
    LGKM0(); SB(); BAR();
  }
#undef GLD
#undef STG
#undef RDAB
#undef MH

  // C-write. C/D layout (round-1 verified): col = lane&15, row = (lane>>4)*4+i
  const float* rs = (MODE == 2) ? (rsInv + (size_t)bz * rsStride) : nullptr;
  const int cr = (l >> 4) * 4, cc = l & 15;
  const long long rowb = r0 + wr * 64, colb = c0 + wc * 64;
#pragma unroll
  for (int m = 0; m < 4; ++m)
#pragma unroll
    for (int n = 0; n < 4; ++n) {
      long long col = colb + n * 16 + cc;
#pragma unroll
      for (int i2 = 0; i2 < 4; ++i2) {
        long long row = rowb + m * 16 + cr + i2;
        float v = acc[m][n][i2] * scale;
        if constexpr (MODE == 1) {
          store_out(&C[row * ldc + col], __expf(v));
        } else if constexpr (MODE == 2) {
          store_out(&C[row * ldc + col], v * rs[row]);
        } else {
          store_out(&C[row * ldc + col], v);
        }
      }
    }
}

// ---------------- workspace layout (bytes, all 256-aligned) ----------------
static const size_t OFF_XB  = 0;            // x bf16        16,777,216
static const size_t OFF_WQ  = 16777216;     // weights bf16   4 x 2,097,152
static const size_t OFF_WO  = 23068672;
static const size_t OFF_Q   = 25165824;     // Q bf16        16,777,216
static const size_t OFF_K   = 41943040;     // K bf16        16,777,216
static const size_t OFF_VT  = 75497472;     // V^T bf16 [1024][8192]
static const size_t OFF_RS  = 92274688;     // rowsumInv f32     32,768
static const size_t OFF_P   = 159383552;    // expS bf16     33,554,432
static const size_t OFF_CTX = 192937984;    // ctx bf16      16,777,216
static const size_t WS_NEED = 209715200;    // 200 MiB

extern "C" void kernel_launch(void* const* d_in, const int* in_sizes, int n_in,
                              void* d_out, int out_size, void* d_ws, size_t ws_size,
                              hipStream_t stream) {
  const float* x  = (const float*)d_in[0];
  const float* wq = (const float*)d_in[1];
  const float* wk = (const float*)d_in[2];
  const float* wv = (const float*)d_in[3];
  const float* wo = (const float*)d_in[4];
  float* out = (float*)d_out;

  if (ws_size < WS_NEED) {
    fprintf(stderr, "kernel_launch: ws_size=%zu < needed %zu\n", ws_size, WS_NEED);
    return;
  }
  char* ws = (char*)d_ws;
  unsigned short* xb  = (unsigned short*)(ws + OFF_XB);
  unsigned short* wqb = (unsigned short*)(ws + OFF_WQ);   // wq,wk,wv,wo contiguous
  unsigned short* wvb = wqb + 2 * 1048576;
  unsigned short* wob = (unsigned short*)(ws + OFF_WO);
  unsigned short* Qb  = (unsigned short*)(ws + OFF_Q);
  unsigned short* Vt  = (unsigned short*)(ws + OFF_VT);
  float*          rs  = (float*)(ws + OFF_RS);
  unsigned short* Pb  = (unsigned short*)(ws + OFF_P);
  unsigned short* Cx  = (unsigned short*)(ws + OFF_CTX);

  // 1) convert x + all 4 weights to bf16 (one launch)
  cvt_all<<<12288, 256, 0, stream>>>(x, wq, wk, wv, wo, xb, wqb);

  // 2) fused Q,K: z selects weight (bStride) and output (cStride); 1024 blocks
  gemmP<unsigned short, 0><<<dim3(8, 64, 2), 256, 0, stream>>>(
      xb, wqb, Qb, 1024, 1024, 1024, 16, 0, 1048576LL, 8388608LL, 1.0f,
      nullptr, 0);

  // 3) V^T directly: Vt[e][s] = sum_d Wv[e,d] x[s,d]; M=1024, N=8192; 512 blocks
  gemmP<unsigned short, 0><<<dim3(64, 8, 1), 256, 0, stream>>>(
      wvb, xb, Vt, 1024, 1024, 8192, 16, 0, 0, 0, 1.0f, nullptr, 0);

  // 4) expS = exp(Q @ K^T / 32) -> bf16 (per batch, M=N=2048, K=1024); 1024 blocks
  gemmP<unsigned short, 1><<<dim3(16, 16, 4), 256, 0, stream>>>(
      Qb, Qb + 8388608, Pb, 1024, 1024, 2048, 16,
      2097152LL, 2097152LL, 4194304LL, 0.03125f, nullptr, 0);

  // 5) rowsumInv (wave per row); 2048 blocks
  rowsum_inv<<<2048, 256, 0, stream>>>(Pb, rs);

  // 6) ctx = (expS @ V) * rsInv  (per batch, M=2048, N=1024, K=2048); 512 blocks
  gemmP<unsigned short, 2><<<dim3(8, 16, 4), 256, 0, stream>>>(
      Pb, Vt, Cx, 2048, 8192, 1024, 32,
      4194304LL, 2048LL, 2097152LL, 1.0f, rs, 2048LL);

  // 7) out = ctx @ wo^T  (M=8192, N=1024, K=1024); 512 blocks
  gemmP<float, 0><<<dim3(8, 64, 1), 256, 0, stream>>>(
      Cx, wob, out, 1024, 1024, 1024, 16, 0, 0, 0, 1.0f, nullptr, 0);
}